// Round 1
// baseline (925.664 us; speedup 1.0000x reference)
//
#include <hip/hip_runtime.h>
#include <hip/hip_bf16.h>
#include <math.h>

// ---------------------------------------------------------------------------
// GCN: 4 x [h = tanh(Dis (A+I) Dis (x W) + b)], then h @ W_out + b_out
// N=100k nodes, E=1M edges, D=64, D_out=16, all fp32.
// Strategy: build CSR-by-dst once per launch, then per layer:
//   g = dis[n] * (x @ W)          (wave-per-node GEMM, W in LDS, shfl bcast)
//   out[n] = tanh(dis[n]*(g[n] + sum_{src in in(n)} g[src]) + b)
// ---------------------------------------------------------------------------

__device__ __forceinline__ float tanh_fast(float x) {
    // tanh(x) = 1 - 2/(e^{2x}+1); robust: x->+inf => 1, x->-inf => -1
    float e = __expf(2.0f * x);
    return 1.0f - 2.0f / (e + 1.0f);
}

// ---- degree count (int atomics) -------------------------------------------
__global__ void __launch_bounds__(256) deg_kernel(const int* __restrict__ dst,
                                                  int* __restrict__ deg, int E) {
    int i = blockIdx.x * 256 + threadIdx.x;
    if (i < E) atomicAdd(&deg[dst[i]], 1);
}

// ---- dis = rsqrt(deg + 1) --------------------------------------------------
__global__ void __launch_bounds__(256) dis_kernel(const int* __restrict__ deg,
                                                  float* __restrict__ dis, int n) {
    int i = blockIdx.x * 256 + threadIdx.x;
    if (i < n) dis[i] = rsqrtf((float)deg[i] + 1.0f);
}

// ---- blockwise exclusive scan of deg -> off --------------------------------
__global__ void __launch_bounds__(1024) scan1_kernel(const int* __restrict__ deg,
                                                     int* __restrict__ off,
                                                     int* __restrict__ csum, int n) {
    __shared__ int s[1024];
    int t = threadIdx.x;
    int i = blockIdx.x * 1024 + t;
    int v = (i < n) ? deg[i] : 0;
    s[t] = v;
    __syncthreads();
    #pragma unroll
    for (int o = 1; o < 1024; o <<= 1) {
        int a = 0;
        if (t >= o) a = s[t - o];
        __syncthreads();
        if (t >= o) s[t] += a;
        __syncthreads();
    }
    if (i < n) off[i] = s[t] - v;          // exclusive
    if (t == 1023) csum[blockIdx.x] = s[1023];
}

__global__ void scan2_kernel(int* __restrict__ csum, int nc) {
    if (threadIdx.x == 0 && blockIdx.x == 0) {
        int run = 0;
        for (int c = 0; c < nc; ++c) { int t = csum[c]; csum[c] = run; run += t; }
    }
}

__global__ void __launch_bounds__(1024) scan3_kernel(int* __restrict__ off,
                                                     const int* __restrict__ csum,
                                                     int n, int E) {
    int i = blockIdx.x * 1024 + threadIdx.x;
    if (i < n) off[i] += csum[blockIdx.x];
    if (i == 0) off[n] = E;
}

// ---- fill CSR src lists ----------------------------------------------------
__global__ void __launch_bounds__(256) fill_kernel(const int* __restrict__ src,
                                                   const int* __restrict__ dst,
                                                   const int* __restrict__ off,
                                                   int* __restrict__ cursor,
                                                   int* __restrict__ srcl, int E) {
    int i = blockIdx.x * 256 + threadIdx.x;
    if (i < E) {
        int d = dst[i];
        int pos = atomicAdd(&cursor[d], 1);
        srcl[off[d] + pos] = src[i];
    }
}

// ---- g[n][d] = dis[n] * sum_k x[n][k] * W[k][d] ----------------------------
__global__ void __launch_bounds__(256) gemm_g_kernel(const float* __restrict__ x,
                                                     const float* __restrict__ W,
                                                     const float* __restrict__ dis,
                                                     float* __restrict__ g, int n) {
    __shared__ float Wl[4096];
    int t = threadIdx.x;
    #pragma unroll
    for (int i = 0; i < 16; ++i) Wl[t + i * 256] = W[t + i * 256];
    __syncthreads();
    int lane = t & 63;
    int wslot = (blockIdx.x << 2) + (t >> 6);
    int stride = gridDim.x << 2;
    for (int node = wslot; node < n; node += stride) {
        float xv = x[(node << 6) + lane];
        float acc = 0.0f;
        #pragma unroll
        for (int k = 0; k < 64; ++k)
            acc = fmaf(__shfl(xv, k), Wl[(k << 6) + lane], acc);
        g[(node << 6) + lane] = dis[node] * acc;
    }
}

// ---- out[n][d] = tanh(dis[n]*(g[n][d] + sum_in g[src][d]) + b[d]) ----------
__global__ void __launch_bounds__(256) agg_kernel(const float* __restrict__ g,
                                                  const float* __restrict__ dis,
                                                  const int* __restrict__ off,
                                                  const int* __restrict__ srcl,
                                                  const float* __restrict__ bias,
                                                  float* __restrict__ out, int n) {
    int t = threadIdx.x, lane = t & 63;
    int node = (blockIdx.x << 2) + (t >> 6);
    if (node >= n) return;
    int e0 = off[node], e1 = off[node + 1];
    float s = g[(node << 6) + lane];
    for (int e = e0; e < e1; ++e) {
        int sidx = srcl[e];
        s += g[(sidx << 6) + lane];
    }
    out[(node << 6) + lane] = tanh_fast(dis[node] * s + bias[lane]);
}

// ---- final: out[n][j] = sum_k h[n][k]*Wo[k][j] + bo[j], j<16 ---------------
__global__ void __launch_bounds__(256) final_kernel(const float* __restrict__ h,
                                                    const float* __restrict__ Wo,
                                                    const float* __restrict__ bo,
                                                    float* __restrict__ out, int n) {
    __shared__ float Wl[1024];
    __shared__ float bl[16];
    __shared__ float hs[16 * 68];   // pad stride 68 to dodge bank conflicts
    int t = threadIdx.x;
    for (int i = t; i < 1024; i += 256) Wl[i] = Wo[i];
    if (t < 16) bl[t] = bo[t];
    int nodeBase = blockIdx.x * 16;
    // stage 16 node rows (coalesced)
    for (int i = t; i < 1024; i += 256) {
        int nn = i >> 6, kk = i & 63;
        if (nodeBase + nn < n) hs[nn * 68 + kk] = h[(nodeBase + nn) * 64 + kk];
    }
    __syncthreads();
    int nsub = t >> 4;      // 0..15
    int j = t & 15;
    int node = nodeBase + nsub;
    if (node >= n) return;
    const float* hr = hs + nsub * 68;
    float acc = bl[j];
    #pragma unroll
    for (int k = 0; k < 64; ++k) acc = fmaf(hr[k], Wl[k * 16 + j], acc);
    out[node * 16 + j] = acc;
}

// ---------------------------------------------------------------------------
extern "C" void kernel_launch(void* const* d_in, const int* in_sizes, int n_in,
                              void* d_out, int out_size, void* d_ws, size_t ws_size,
                              hipStream_t stream) {
    const float* x     = (const float*)d_in[0];
    const int*   ei    = (const int*)d_in[1];   // (2, E) int32
    const float* W[4]  = {(const float*)d_in[2], (const float*)d_in[4],
                          (const float*)d_in[6], (const float*)d_in[8]};
    const float* B[4]  = {(const float*)d_in[3], (const float*)d_in[5],
                          (const float*)d_in[7], (const float*)d_in[9]};
    const float* Wo    = (const float*)d_in[10];
    const float* bo    = (const float*)d_in[11];
    float* out         = (float*)d_out;

    const int N = in_sizes[0] / 64;
    const int E = in_sizes[1] / 2;
    const int* srcp = ei;          // row 0
    const int* dstp = ei + E;      // row 1

    // workspace layout (256B aligned chunks)
    char* w = (char*)d_ws;
    size_t o = 0;
    auto alloc = [&](size_t bytes) { void* p = w + o; o = (o + bytes + 255) & ~(size_t)255; return p; };
    float* dis    = (float*)alloc((size_t)N * 4);
    int*   degi   = (int*)  alloc((size_t)N * 4);
    int*   off    = (int*)  alloc((size_t)(N + 1) * 4);
    int*   cursor = (int*)  alloc((size_t)N * 4);
    int*   csum   = (int*)  alloc(1024);
    int*   srcl   = (int*)  alloc((size_t)E * 4);
    float* bufA   = (float*)alloc((size_t)N * 64 * 4);
    float* bufB   = (float*)alloc((size_t)N * 64 * 4);

    hipMemsetAsync(degi,   0, (size_t)N * 4, stream);
    hipMemsetAsync(cursor, 0, (size_t)N * 4, stream);

    int ge = (E + 255) / 256;
    int gn = (N + 255) / 256;
    int nchunks = (N + 1023) / 1024;

    deg_kernel<<<ge, 256, 0, stream>>>(dstp, degi, E);
    dis_kernel<<<gn, 256, 0, stream>>>(degi, dis, N);
    scan1_kernel<<<nchunks, 1024, 0, stream>>>(degi, off, csum, N);
    scan2_kernel<<<1, 64, 0, stream>>>(csum, nchunks);
    scan3_kernel<<<nchunks, 1024, 0, stream>>>(off, csum, N, E);
    fill_kernel<<<ge, 256, 0, stream>>>(srcp, dstp, off, cursor, srcl, E);

    int gemm_blocks = 2048;                 // grid-stride, 4 waves/block
    int agg_blocks  = (N + 3) / 4;          // one wave per node

    const float* cur = x;
    for (int l = 0; l < 4; ++l) {
        gemm_g_kernel<<<gemm_blocks, 256, 0, stream>>>(cur, W[l], dis, bufA, N);
        agg_kernel<<<agg_blocks, 256, 0, stream>>>(bufA, dis, off, srcl, B[l], bufB, N);
        cur = bufB;
    }
    final_kernel<<<(N + 15) / 16, 256, 0, stream>>>(bufB, Wo, bo, out, N);
}

// Round 2
// 502.581 us; speedup vs baseline: 1.8418x; 1.8418x over previous
//
#include <hip/hip_runtime.h>
#include <hip/hip_bf16.h>
#include <math.h>

// ---------------------------------------------------------------------------
// GCN: 4 x [h = tanh(Dis (A+I) Dis (x W) + b)], then h @ W_out + b_out
// N=100k nodes, E=1M edges, D=64, D_out=16, all fp32.
//   g = dis[n] * (x @ W)     (lane-owns-column GEMM, W in regs, LDS x-bcast)
//   h[n] = tanh(dis[n]*(g[n] + sum_{src in in(n)} g[src]) + b)
//   agg: 4 nodes/wave (16-lane quarters, float4), unroll-4 gathers for MLP
// ---------------------------------------------------------------------------

__device__ __forceinline__ float tanh_fast(float x) {
    float e = __expf(2.0f * x);
    return 1.0f - 2.0f / (e + 1.0f);
}

// ---- degree count (int atomics) -------------------------------------------
__global__ void __launch_bounds__(256) deg_kernel(const int* __restrict__ dst,
                                                  int* __restrict__ deg, int E) {
    int i = blockIdx.x * 256 + threadIdx.x;
    if (i < E) atomicAdd(&deg[dst[i]], 1);
}

// ---- dis = rsqrt(deg + 1) --------------------------------------------------
__global__ void __launch_bounds__(256) dis_kernel(const int* __restrict__ deg,
                                                  float* __restrict__ dis, int n) {
    int i = blockIdx.x * 256 + threadIdx.x;
    if (i < n) dis[i] = rsqrtf((float)deg[i] + 1.0f);
}

// ---- blockwise exclusive scan of deg -> off --------------------------------
__global__ void __launch_bounds__(1024) scan1_kernel(const int* __restrict__ deg,
                                                     int* __restrict__ off,
                                                     int* __restrict__ csum, int n) {
    __shared__ int s[1024];
    int t = threadIdx.x;
    int i = blockIdx.x * 1024 + t;
    int v = (i < n) ? deg[i] : 0;
    s[t] = v;
    __syncthreads();
    #pragma unroll
    for (int o = 1; o < 1024; o <<= 1) {
        int a = 0;
        if (t >= o) a = s[t - o];
        __syncthreads();
        if (t >= o) s[t] += a;
        __syncthreads();
    }
    if (i < n) off[i] = s[t] - v;          // exclusive
    if (t == 1023) csum[blockIdx.x] = s[1023];
}

// ---- single-block parallel exclusive scan of chunk sums --------------------
__global__ void __launch_bounds__(1024) scan2_kernel(int* __restrict__ csum, int nc) {
    __shared__ int s[1024];
    int t = threadIdx.x;
    int v = (t < nc) ? csum[t] : 0;
    s[t] = v;
    __syncthreads();
    #pragma unroll
    for (int o = 1; o < 1024; o <<= 1) {
        int a = 0;
        if (t >= o) a = s[t - o];
        __syncthreads();
        if (t >= o) s[t] += a;
        __syncthreads();
    }
    if (t < nc) csum[t] = s[t] - v;        // exclusive
}

__global__ void __launch_bounds__(1024) scan3_kernel(int* __restrict__ off,
                                                     const int* __restrict__ csum,
                                                     int n, int E) {
    int i = blockIdx.x * 1024 + threadIdx.x;
    if (i < n) off[i] += csum[blockIdx.x];
    if (i == 0) off[n] = E;
}

// ---- fill CSR src lists ----------------------------------------------------
__global__ void __launch_bounds__(256) fill_kernel(const int* __restrict__ src,
                                                   const int* __restrict__ dst,
                                                   const int* __restrict__ off,
                                                   int* __restrict__ cursor,
                                                   int* __restrict__ srcl, int E) {
    int i = blockIdx.x * 256 + threadIdx.x;
    if (i < E) {
        int d = dst[i];
        int pos = atomicAdd(&cursor[d], 1);
        srcl[off[d] + pos] = src[i];
    }
}

// ---- g[n][d] = dis[n] * sum_k x[n][k] * W[k][d] ----------------------------
// lane d owns column d (W column in 64 VGPRs); x row broadcast from LDS.
__global__ void __launch_bounds__(256) gemm_g_kernel(const float* __restrict__ x,
                                                     const float* __restrict__ W,
                                                     const float* __restrict__ dis,
                                                     float* __restrict__ g, int n) {
    __shared__ float xs[64 * 64];          // 16 KB: 64 node rows
    int t = threadIdx.x;
    int lane = t & 63;
    int wave = t >> 6;
    float Wr[64];
    #pragma unroll
    for (int k = 0; k < 64; ++k) Wr[k] = W[k * 64 + lane];

    int base = blockIdx.x * 64;
    int limit = n - base;                   // rows available in this tile
    const float4* xg = (const float4*)(x + (size_t)base * 64);
    float4* xsv = (float4*)xs;
    #pragma unroll
    for (int i = 0; i < 4; ++i) {
        int idx = t + i * 256;              // float4 index (0..1023), row=idx>>4
        if ((idx >> 4) < limit) xsv[idx] = xg[idx];
    }
    __syncthreads();

    int i0 = wave * 16;
    for (int i = i0; i < i0 + 16; ++i) {
        int node = base + i;
        if (node >= n) break;
        const float4* xr = (const float4*)(xs + i * 64);
        float a0 = 0.f, a1 = 0.f, a2 = 0.f, a3 = 0.f;
        #pragma unroll
        for (int k4 = 0; k4 < 16; ++k4) {
            float4 xv = xr[k4];             // wave-uniform addr -> broadcast
            a0 = fmaf(xv.x, Wr[4 * k4 + 0], a0);
            a1 = fmaf(xv.y, Wr[4 * k4 + 1], a1);
            a2 = fmaf(xv.z, Wr[4 * k4 + 2], a2);
            a3 = fmaf(xv.w, Wr[4 * k4 + 3], a3);
        }
        g[(size_t)node * 64 + lane] = dis[node] * ((a0 + a1) + (a2 + a3));
    }
}

// ---- h[n][d] = tanh(dis[n]*(g[n][d] + sum_in g[src][d]) + b[d]) ------------
// 4 nodes per wave: 16-lane quarters, float4/lane, unroll-4 gathers.
__global__ void __launch_bounds__(256) agg_kernel(const float* __restrict__ g,
                                                  const float* __restrict__ dis,
                                                  const int* __restrict__ off,
                                                  const int* __restrict__ srcl,
                                                  const float* __restrict__ bias,
                                                  float* __restrict__ out, int n) {
    int t = threadIdx.x;
    int lane = t & 63;
    int q = lane >> 4;                      // quarter 0..3
    int r = lane & 15;                      // lane within quarter
    int node = (blockIdx.x << 4) + ((t >> 6) << 2) + q;
    if (node >= n) return;

    const float4* gv = (const float4*)g;
    float4 s = gv[node * 16 + r];           // self row (pre-scaled by dis[src])
    int e0 = off[node], e1 = off[node + 1];
    int e = e0;
    for (; e + 4 <= e1; e += 4) {
        int i0 = srcl[e + 0], i1 = srcl[e + 1];
        int i2 = srcl[e + 2], i3 = srcl[e + 3];
        float4 a0 = gv[i0 * 16 + r];
        float4 a1 = gv[i1 * 16 + r];
        float4 a2 = gv[i2 * 16 + r];
        float4 a3 = gv[i3 * 16 + r];
        s.x += (a0.x + a1.x) + (a2.x + a3.x);
        s.y += (a0.y + a1.y) + (a2.y + a3.y);
        s.z += (a0.z + a1.z) + (a2.z + a3.z);
        s.w += (a0.w + a1.w) + (a2.w + a3.w);
    }
    for (; e < e1; ++e) {
        float4 a = gv[srcl[e] * 16 + r];
        s.x += a.x; s.y += a.y; s.z += a.z; s.w += a.w;
    }
    float dn = dis[node];
    float4 b = ((const float4*)bias)[r];
    float4 h;
    h.x = tanh_fast(fmaf(dn, s.x, b.x));
    h.y = tanh_fast(fmaf(dn, s.y, b.y));
    h.z = tanh_fast(fmaf(dn, s.z, b.z));
    h.w = tanh_fast(fmaf(dn, s.w, b.w));
    ((float4*)out)[node * 16 + r] = h;
}

// ---- final: out[n][j] = sum_k h[n][k]*Wo[k][j] + bo[j], j<16 ---------------
__global__ void __launch_bounds__(256) final_kernel(const float* __restrict__ h,
                                                    const float* __restrict__ Wo,
                                                    const float* __restrict__ bo,
                                                    float* __restrict__ out, int n) {
    __shared__ float Wl[1024];
    __shared__ float bl[16];
    __shared__ float hs[16 * 68];
    int t = threadIdx.x;
    for (int i = t; i < 1024; i += 256) Wl[i] = Wo[i];
    if (t < 16) bl[t] = bo[t];
    int nodeBase = blockIdx.x * 16;
    for (int i = t; i < 1024; i += 256) {
        int nn = i >> 6, kk = i & 63;
        if (nodeBase + nn < n) hs[nn * 68 + kk] = h[(nodeBase + nn) * 64 + kk];
    }
    __syncthreads();
    int nsub = t >> 4;
    int j = t & 15;
    int node = nodeBase + nsub;
    if (node >= n) return;
    const float* hr = hs + nsub * 68;
    float acc = bl[j];
    #pragma unroll
    for (int k = 0; k < 64; ++k) acc = fmaf(hr[k], Wl[k * 16 + j], acc);
    out[node * 16 + j] = acc;
}

// ---------------------------------------------------------------------------
extern "C" void kernel_launch(void* const* d_in, const int* in_sizes, int n_in,
                              void* d_out, int out_size, void* d_ws, size_t ws_size,
                              hipStream_t stream) {
    const float* x     = (const float*)d_in[0];
    const int*   ei    = (const int*)d_in[1];   // (2, E) int32
    const float* W[4]  = {(const float*)d_in[2], (const float*)d_in[4],
                          (const float*)d_in[6], (const float*)d_in[8]};
    const float* B[4]  = {(const float*)d_in[3], (const float*)d_in[5],
                          (const float*)d_in[7], (const float*)d_in[9]};
    const float* Wo    = (const float*)d_in[10];
    const float* bo    = (const float*)d_in[11];
    float* out         = (float*)d_out;

    const int N = in_sizes[0] / 64;
    const int E = in_sizes[1] / 2;
    const int* srcp = ei;
    const int* dstp = ei + E;

    char* w = (char*)d_ws;
    size_t o = 0;
    auto alloc = [&](size_t bytes) { void* p = w + o; o = (o + bytes + 255) & ~(size_t)255; return p; };
    float* dis    = (float*)alloc((size_t)N * 4);
    int*   degi   = (int*)  alloc((size_t)N * 4);
    int*   off    = (int*)  alloc((size_t)(N + 1) * 4);
    int*   cursor = (int*)  alloc((size_t)N * 4);
    int*   csum   = (int*)  alloc(4096);
    int*   srcl   = (int*)  alloc((size_t)E * 4);
    float* bufA   = (float*)alloc((size_t)N * 64 * 4);
    float* bufB   = (float*)alloc((size_t)N * 64 * 4);

    hipMemsetAsync(degi,   0, (size_t)N * 4, stream);
    hipMemsetAsync(cursor, 0, (size_t)N * 4, stream);

    int ge = (E + 255) / 256;
    int gn = (N + 255) / 256;
    int nchunks = (N + 1023) / 1024;

    deg_kernel<<<ge, 256, 0, stream>>>(dstp, degi, E);
    dis_kernel<<<gn, 256, 0, stream>>>(degi, dis, N);
    scan1_kernel<<<nchunks, 1024, 0, stream>>>(degi, off, csum, N);
    scan2_kernel<<<1, 1024, 0, stream>>>(csum, nchunks);
    scan3_kernel<<<nchunks, 1024, 0, stream>>>(off, csum, N, E);
    fill_kernel<<<ge, 256, 0, stream>>>(srcp, dstp, off, cursor, srcl, E);

    int gemm_blocks = (N + 63) / 64;
    int agg_blocks  = (N + 15) / 16;

    const float* cur = x;
    for (int l = 0; l < 4; ++l) {
        gemm_g_kernel<<<gemm_blocks, 256, 0, stream>>>(cur, W[l], dis, bufA, N);
        agg_kernel<<<agg_blocks, 256, 0, stream>>>(bufA, dis, off, srcl, B[l], bufB, N);
        cur = bufB;
    }
    final_kernel<<<(N + 15) / 16, 256, 0, stream>>>(bufB, Wo, bo, out, N);
}